// Round 10
// baseline (4044.947 us; speedup 1.0000x reference)
//
#include <hip/hip_runtime.h>

#define TLEN 1024
#define HID  96
#define NTHR 768

__device__ __forceinline__ float sigf(float x) { return 1.0f / (1.0f + __expf(-x)); }
__device__ __forceinline__ float tanh_fast(float x) {
    float e = __expf(2.0f * x);
    return 1.0f - 2.0f / (e + 1.0f);
}

// VALU-pipe lane combine: s += s(from lane per dpp_ctrl). No LDS pipe use.
template <int CTRL>
__device__ __forceinline__ float dpp_add(float s) {
    int t = __builtin_amdgcn_update_dpp(0, __float_as_int(s), CTRL, 0xF, 0xF, true);
    return s + __int_as_float(t);
}
#define DPP_XOR1   0xB1   // quad_perm [1,0,3,2]: lane i <- lane i^1
#define DPP_XOR2   0x4E   // quad_perm [2,3,0,1]: lane i <- lane i^2
#define DPP_HMIRR  0x141  // row_half_mirror: lane i <- (i&~7)+(7-(i&7)); direction-proof
#define DPP_ROR8   0x128  // row_ror:8: lane i <- lane (i-8)&15 == (i+8)&15 (symmetric)

// 8-lane reduce -> correct full sum in lanes kq==0 (i.e. lanes 0,8 of each 16-row).
// R9 bug: row_ror:4 sources lane (i-4)&15 (AMD DPP "right" moves data UP-lane),
// which crossed unit groups. HALF_MIRROR has no direction ambiguity: lane0<-lane7.
#define RED8(S)  S = dpp_add<DPP_XOR1>(S); S = dpp_add<DPP_XOR2>(S); S = dpp_add<DPP_HMIRR>(S);

#define DOT4(A, W, H)                         \
    (A).x = fmaf((W).x, (H).x, (A).x);        \
    (A).y = fmaf((W).y, (H).y, (A).y);        \
    (A).z = fmaf((W).z, (H).z, (A).z);        \
    (A).w = fmaf((W).w, (H).w, (A).w);

extern "C" __global__ void __launch_bounds__(NTHR)
__attribute__((amdgpu_waves_per_eu(3, 3)))
lstm2_fused(const float* __restrict__ x,
            const float* __restrict__ Wih0, const float* __restrict__ Whh0,
            const float* __restrict__ bih0, const float* __restrict__ bhh0,
            const float* __restrict__ Wih1, const float* __restrict__ Whh1,
            const float* __restrict__ bih1, const float* __restrict__ bhh1,
            const float* __restrict__ Wl,   const float* __restrict__ bl,
            float* __restrict__ out)
{
    __shared__ __attribute__((aligned(16))) float x_s[TLEN];
    __shared__ __attribute__((aligned(16))) float out_s[TLEN];
    __shared__ __attribute__((aligned(16))) float h1b[2 * HID];  // double-buffered
    __shared__ __attribute__((aligned(16))) float h2b[2 * HID];
    // Pad LDS past 80KB -> exactly 1 block/CU -> scheduler budget = 3 waves/EU.
    __shared__ float ldspad[18432];

    const int tid = threadIdx.x;
    const int b   = blockIdx.x;
    const int u   = tid >> 3;   // unit 0..95
    const int kq  = tid & 7;    // K-slice index 0..7

    ((volatile float*)ldspad)[tid] = 0.0f;  // keep pad allocated

    for (int i = tid; i < TLEN; i += NTHR) {
        x_s[i]   = x[b * TLEN + i];
        out_s[i] = 0.0f;
    }
    if (tid < 2 * HID) { h1b[tid] = 0.0f; h2b[tid] = 0.0f; }

    // ---- Layer-1 weights: gate g row = 96g+u, f4-cols [3kq, 3kq+3) of 24 ----
    const float4* W0 = reinterpret_cast<const float4*>(Whh0);
    const float4* p;
    p = W0 + (      u) * 24 + 3 * kq;  float4 a00 = p[0], a01 = p[1], a02 = p[2];
    p = W0 + ( 96 + u) * 24 + 3 * kq;  float4 a10 = p[0], a11 = p[1], a12 = p[2];
    p = W0 + (192 + u) * 24 + 3 * kq;  float4 a20 = p[0], a21 = p[1], a22 = p[2];
    p = W0 + (288 + u) * 24 + 3 * kq;  float4 a30 = p[0], a31 = p[1], a32 = p[2];

    // ---- Layer-2 weights: K=192=[Wih1|Whh1]; kq<4 -> Wih1 cols 24kq.., else Whh1 ----
    const float4* W1 = reinterpret_cast<const float4*>(kq < 4 ? Wih1 : Whh1);
    const int c6 = 6 * (kq & 3);
    p = W1 + (      u) * 24 + c6;  float4 b00=p[0],b01=p[1],b02=p[2],b03=p[3],b04=p[4],b05=p[5];
    p = W1 + ( 96 + u) * 24 + c6;  float4 b10=p[0],b11=p[1],b12=p[2],b13=p[3],b14=p[4],b15=p[5];
    p = W1 + (192 + u) * 24 + c6;  float4 b20=p[0],b21=p[1],b22=p[2],b23=p[3],b24=p[4],b25=p[5];
    p = W1 + (288 + u) * 24 + c6;  float4 b30=p[0],b31=p[1],b32=p[2],b33=p[3],b34=p[4],b35=p[5];

    // ---- per-lane bias/x-term carriers (enter gate g via lane kq==g pre-reduce) ----
    float biasA = 0.0f, wxA = 0.0f, biasC = 0.0f;
    if (kq < 4) { int r = 96 * kq + u;       biasA = bih0[r] + bhh0[r]; wxA = Wih0[r]; }
    else        { int r = 96 * (kq - 4) + u; biasC = bih1[r] + bhh1[r]; }
    const float m0  = (kq == 0) ? 1.0f : 0.0f;
    const float m1  = (kq == 1) ? 1.0f : 0.0f;
    const float m2  = (kq == 2) ? 1.0f : 0.0f;
    const float m3  = (kq == 3) ? 1.0f : 0.0f;
    const float mc0 = (kq == 4) ? 1.0f : 0.0f;
    const float mc1 = (kq == 5) ? 1.0f : 0.0f;
    const float mc2 = (kq == 6) ? 1.0f : 0.0f;
    const float mc3 = (kq == 7) ? 1.0f : 0.0f;
    const float wl_u = (kq == 0) ? Wl[u] : 0.0f;
    const float bl0  = bl[0];

    float c1 = 0.0f, c2 = 0.0f;   // cell state, valid in lane kq==0 only
    __syncthreads();

    #pragma unroll 1
    for (int t = 0; t < TLEN; ++t) {
        const int rd = t & 1, wb = rd ^ 1;
        const float xt = x_s[t];

        // ---- Layer 1: 4 gate partial-dots over cols [12kq,12kq+12) ----
        {
            const float4* hA = reinterpret_cast<const float4*>(h1b + rd * HID) + 3 * kq;
            float4 q0 = {0,0,0,0}, q1 = {0,0,0,0}, q2 = {0,0,0,0}, q3 = {0,0,0,0};
            float4 h4;
            h4 = hA[0]; DOT4(q0,a00,h4) DOT4(q1,a10,h4) DOT4(q2,a20,h4) DOT4(q3,a30,h4)
            h4 = hA[1]; DOT4(q0,a01,h4) DOT4(q1,a11,h4) DOT4(q2,a21,h4) DOT4(q3,a31,h4)
            h4 = hA[2]; DOT4(q0,a02,h4) DOT4(q1,a12,h4) DOT4(q2,a22,h4) DOT4(q3,a32,h4)
            float s0 = (q0.x + q0.y) + (q0.z + q0.w);
            float s1 = (q1.x + q1.y) + (q1.z + q1.w);
            float s2 = (q2.x + q2.y) + (q2.z + q2.w);
            float s3 = (q3.x + q3.y) + (q3.z + q3.w);
            const float bwx = fmaf(wxA, xt, biasA);
            s0 = fmaf(m0, bwx, s0); s1 = fmaf(m1, bwx, s1);
            s2 = fmaf(m2, bwx, s2); s3 = fmaf(m3, bwx, s3);
            // converge 8 lanes -> lane kq==0 (VALU DPP, no LDS pipe)
            RED8(s0) RED8(s1) RED8(s2) RED8(s3)
            if (kq == 0) {
                float gi = sigf(s0), gf = sigf(s1), gc = tanh_fast(s2), go = sigf(s3);
                c1 = gf * c1 + gi * gc;
                h1b[wb * HID + u] = go * tanh_fast(c1);
            }
        }
        __syncthreads();   // the ONLY barrier per step
        // ---- Layer 2: cols [24kq..): kq<4 over h1_t (new), kq>=4 over h2_{t-1} ----
        {
            const float4* hC = (kq < 4)
                ? reinterpret_cast<const float4*>(h1b + wb * HID) + 6 * kq
                : reinterpret_cast<const float4*>(h2b + rd * HID) + 6 * (kq - 4);
            float4 q0 = {0,0,0,0}, q1 = {0,0,0,0}, q2 = {0,0,0,0}, q3 = {0,0,0,0};
            float4 h4;
            h4 = hC[0]; DOT4(q0,b00,h4) DOT4(q1,b10,h4) DOT4(q2,b20,h4) DOT4(q3,b30,h4)
            h4 = hC[1]; DOT4(q0,b01,h4) DOT4(q1,b11,h4) DOT4(q2,b21,h4) DOT4(q3,b31,h4)
            h4 = hC[2]; DOT4(q0,b02,h4) DOT4(q1,b12,h4) DOT4(q2,b22,h4) DOT4(q3,b32,h4)
            h4 = hC[3]; DOT4(q0,b03,h4) DOT4(q1,b13,h4) DOT4(q2,b23,h4) DOT4(q3,b33,h4)
            h4 = hC[4]; DOT4(q0,b04,h4) DOT4(q1,b14,h4) DOT4(q2,b24,h4) DOT4(q3,b34,h4)
            h4 = hC[5]; DOT4(q0,b05,h4) DOT4(q1,b15,h4) DOT4(q2,b25,h4) DOT4(q3,b35,h4)
            float s0 = (q0.x + q0.y) + (q0.z + q0.w);
            float s1 = (q1.x + q1.y) + (q1.z + q1.w);
            float s2 = (q2.x + q2.y) + (q2.z + q2.w);
            float s3 = (q3.x + q3.y) + (q3.z + q3.w);
            s0 = fmaf(mc0, biasC, s0); s1 = fmaf(mc1, biasC, s1);
            s2 = fmaf(mc2, biasC, s2); s3 = fmaf(mc3, biasC, s3);
            RED8(s0) RED8(s1) RED8(s2) RED8(s3)
            float po = 0.0f;
            if (kq == 0) {
                float gi = sigf(s0), gf = sigf(s1), gc = tanh_fast(s2), go = sigf(s3);
                c2 = gf * c2 + gi * gc;
                float h2v = go * tanh_fast(c2);
                h2b[wb * HID + u] = h2v;
                po = wl_u * h2v;
            }
            // wave-sum of the 8 unit-leaders, then one atomic per wave
            po = dpp_add<DPP_ROR8>(po);     // ror:8 is symmetric mod 16 -> safe
            po += __shfl_xor(po, 16);
            po += __shfl_xor(po, 32);
            if ((tid & 63) == 0) atomicAdd(&out_s[t], po + ((tid == 0) ? bl0 : 0.0f));
        }
        // no trailing barrier needed: next step's L1 writes h1b[rd], which no
        // thread reads after this step's barrier (L2 reads h1b[wb]/h2b[rd]),
        // and all threads left L1(t) before the barrier released anyone.
    }
    __syncthreads();
    for (int i = tid; i < TLEN; i += NTHR) out[b * TLEN + i] = out_s[i];
}

extern "C" void kernel_launch(void* const* d_in, const int* in_sizes, int n_in,
                              void* d_out, int out_size, void* d_ws, size_t ws_size,
                              hipStream_t stream)
{
    (void)in_sizes; (void)n_in; (void)d_ws; (void)ws_size; (void)out_size;
    const float* x    = (const float*)d_in[0];
    const float* Wih0 = (const float*)d_in[1];
    const float* Whh0 = (const float*)d_in[2];
    const float* bih0 = (const float*)d_in[3];
    const float* bhh0 = (const float*)d_in[4];
    const float* Wih1 = (const float*)d_in[5];
    const float* Whh1 = (const float*)d_in[6];
    const float* bih1 = (const float*)d_in[7];
    const float* bhh1 = (const float*)d_in[8];
    const float* Wl   = (const float*)d_in[9];
    const float* bl   = (const float*)d_in[10];

    lstm2_fused<<<dim3(256), dim3(NTHR), 0, stream>>>(
        x, Wih0, Whh0, bih0, bhh0, Wih1, Whh1, bih1, bhh1, Wl, bl,
        (float*)d_out);
}

// Round 11
// 3227.877 us; speedup vs baseline: 1.2531x; 1.2531x over previous
//
#include <hip/hip_runtime.h>

#define TLEN 1024
#define HID  96
#define NTHR 768
#define WPAD 28   // LDS weight row stride (floats): 112B, 16B-aligned, bank-spread

__device__ __forceinline__ float sigf(float x) { return 1.0f / (1.0f + __expf(-x)); }
__device__ __forceinline__ float tanh_fast(float x) {
    float e = __expf(2.0f * x);
    return 1.0f - 2.0f / (e + 1.0f);
}

// VALU-pipe lane combine: s += s(from lane per dpp_ctrl). No LDS pipe use.
template <int CTRL>
__device__ __forceinline__ float dpp_add(float s) {
    int t = __builtin_amdgcn_update_dpp(0, __float_as_int(s), CTRL, 0xF, 0xF, true);
    return s + __int_as_float(t);
}
#define DPP_XOR1   0xB1   // quad_perm [1,0,3,2]: lane i <- lane i^1
#define DPP_XOR2   0x4E   // quad_perm [2,3,0,1]: lane i <- lane i^2
#define DPP_HMIRR  0x141  // row_half_mirror: lane i <- (i&~7)+(7-(i&7))
#define DPP_ROR8   0x128  // row_ror:8 (symmetric mod 16)

#define RED8(S)  S = dpp_add<DPP_XOR1>(S); S = dpp_add<DPP_XOR2>(S); S = dpp_add<DPP_HMIRR>(S);

#define DOT4(A, W, H)                         \
    (A).x = fmaf((W).x, (H).x, (A).x);        \
    (A).y = fmaf((W).y, (H).y, (A).y);        \
    (A).z = fmaf((W).z, (H).z, (A).z);        \
    (A).w = fmaf((W).w, (H).w, (A).w);

extern "C" __global__ void __launch_bounds__(NTHR)
__attribute__((amdgpu_waves_per_eu(3, 3)))
lstm2_fused(const float* __restrict__ x,
            const float* __restrict__ Wih0, const float* __restrict__ Whh0,
            const float* __restrict__ bih0, const float* __restrict__ bhh0,
            const float* __restrict__ Wih1, const float* __restrict__ Whh1,
            const float* __restrict__ bih1, const float* __restrict__ bhh1,
            const float* __restrict__ Wl,   const float* __restrict__ bl,
            float* __restrict__ out)
{
    __shared__ __attribute__((aligned(16))) float x_s[TLEN];
    __shared__ __attribute__((aligned(16))) float out_s[TLEN];
    __shared__ __attribute__((aligned(16))) float h1b[2 * HID];  // double-buffered
    __shared__ __attribute__((aligned(16))) float h2b[2 * HID];
    // gate-o layer-2 weights live here: keeps per-thread reg demand at R7's
    // proven 120 floats (R10's 144 forced per-step scratch spills: 3.1 GB writes).
    // Also pushes LDS to ~93.5 KB -> exactly 1 block/CU.
    __shared__ __attribute__((aligned(16))) float wlds[NTHR * WPAD];  // 86 KB

    const int tid = threadIdx.x;
    const int b   = blockIdx.x;
    const int u   = tid >> 3;   // unit 0..95
    const int kq  = tid & 7;    // K-slice index 0..7

    for (int i = tid; i < TLEN; i += NTHR) {
        x_s[i]   = x[b * TLEN + i];
        out_s[i] = 0.0f;
    }
    if (tid < 2 * HID) { h1b[tid] = 0.0f; h2b[tid] = 0.0f; }

    // ---- Layer-1 weights (regs): gate g row = 96g+u, f4-cols [3kq, 3kq+3) ----
    const float4* W0 = reinterpret_cast<const float4*>(Whh0);
    const float4* p;
    p = W0 + (      u) * 24 + 3 * kq;  float4 a00 = p[0], a01 = p[1], a02 = p[2];
    p = W0 + ( 96 + u) * 24 + 3 * kq;  float4 a10 = p[0], a11 = p[1], a12 = p[2];
    p = W0 + (192 + u) * 24 + 3 * kq;  float4 a20 = p[0], a21 = p[1], a22 = p[2];
    p = W0 + (288 + u) * 24 + 3 * kq;  float4 a30 = p[0], a31 = p[1], a32 = p[2];

    // ---- Layer-2 weights: K=192=[Wih1|Whh1]; kq<4 -> Wih1 cols 24kq.., else Whh1.
    //      Gates i,f,g (18 f4) in regs; gate o (6 f4) -> LDS.
    const float4* W1 = reinterpret_cast<const float4*>(kq < 4 ? Wih1 : Whh1);
    const int c6 = 6 * (kq & 3);
    p = W1 + (      u) * 24 + c6;  float4 b00=p[0],b01=p[1],b02=p[2],b03=p[3],b04=p[4],b05=p[5];
    p = W1 + ( 96 + u) * 24 + c6;  float4 b10=p[0],b11=p[1],b12=p[2],b13=p[3],b14=p[4],b15=p[5];
    p = W1 + (192 + u) * 24 + c6;  float4 b20=p[0],b21=p[1],b22=p[2],b23=p[3],b24=p[4],b25=p[5];
    {
        p = W1 + (288 + u) * 24 + c6;
        float4* wl = reinterpret_cast<float4*>(wlds + tid * WPAD);
        wl[0] = p[0]; wl[1] = p[1]; wl[2] = p[2];
        wl[3] = p[3]; wl[4] = p[4]; wl[5] = p[5];
    }

    // ---- per-lane bias/x-term carriers (enter gate g via lane kq==g pre-reduce) ----
    float biasA = 0.0f, wxA = 0.0f, biasC = 0.0f;
    if (kq < 4) { int r = 96 * kq + u;       biasA = bih0[r] + bhh0[r]; wxA = Wih0[r]; }
    else        { int r = 96 * (kq - 4) + u; biasC = bih1[r] + bhh1[r]; }
    const float m0  = (kq == 0) ? 1.0f : 0.0f;
    const float m1  = (kq == 1) ? 1.0f : 0.0f;
    const float m2  = (kq == 2) ? 1.0f : 0.0f;
    const float m3  = (kq == 3) ? 1.0f : 0.0f;
    const float mc0 = (kq == 4) ? 1.0f : 0.0f;
    const float mc1 = (kq == 5) ? 1.0f : 0.0f;
    const float mc2 = (kq == 6) ? 1.0f : 0.0f;
    const float mc3 = (kq == 7) ? 1.0f : 0.0f;
    const float wl_u = (kq == 0) ? Wl[u] : 0.0f;
    const float bl0  = bl[0];

    float c1 = 0.0f, c2 = 0.0f;   // cell state, valid in lane kq==0 only
    __syncthreads();

    #pragma unroll 1
    for (int t = 0; t < TLEN; ++t) {
        const int rd = t & 1, wb = rd ^ 1;
        const float xt = x_s[t];

        // ---- Layer 1: 4 gate partial-dots over cols [12kq,12kq+12) ----
        {
            const float4* hA = reinterpret_cast<const float4*>(h1b + rd * HID) + 3 * kq;
            float4 q0 = {0,0,0,0}, q1 = {0,0,0,0}, q2 = {0,0,0,0}, q3 = {0,0,0,0};
            float4 h4;
            h4 = hA[0]; DOT4(q0,a00,h4) DOT4(q1,a10,h4) DOT4(q2,a20,h4) DOT4(q3,a30,h4)
            h4 = hA[1]; DOT4(q0,a01,h4) DOT4(q1,a11,h4) DOT4(q2,a21,h4) DOT4(q3,a31,h4)
            h4 = hA[2]; DOT4(q0,a02,h4) DOT4(q1,a12,h4) DOT4(q2,a22,h4) DOT4(q3,a32,h4)
            float s0 = (q0.x + q0.y) + (q0.z + q0.w);
            float s1 = (q1.x + q1.y) + (q1.z + q1.w);
            float s2 = (q2.x + q2.y) + (q2.z + q2.w);
            float s3 = (q3.x + q3.y) + (q3.z + q3.w);
            const float bwx = fmaf(wxA, xt, biasA);
            s0 = fmaf(m0, bwx, s0); s1 = fmaf(m1, bwx, s1);
            s2 = fmaf(m2, bwx, s2); s3 = fmaf(m3, bwx, s3);
            RED8(s0) RED8(s1) RED8(s2) RED8(s3)
            if (kq == 0) {
                float gi = sigf(s0), gf = sigf(s1), gc = tanh_fast(s2), go = sigf(s3);
                c1 = gf * c1 + gi * gc;
                h1b[wb * HID + u] = go * tanh_fast(c1);
            }
        }
        __syncthreads();   // the ONLY barrier per step
        // ---- Layer 2: cols [24kq..): kq<4 over h1_t (new), kq>=4 over h2_{t-1} ----
        {
            const float4* hC = (kq < 4)
                ? reinterpret_cast<const float4*>(h1b + wb * HID) + 6 * kq
                : reinterpret_cast<const float4*>(h2b + rd * HID) + 6 * (kq - 4);
            // gate-o weights stream from LDS; opaque zr keeps the 6 loop-invariant
            // float4s from being LICM-hoisted back into registers (R3/R4 lesson)
            int zr;
            asm volatile("v_mov_b32 %0, 0" : "=v"(zr));
            const float4* wl = reinterpret_cast<const float4*>(wlds + tid * WPAD + zr);
            float4 q0 = {0,0,0,0}, q1 = {0,0,0,0}, q2 = {0,0,0,0}, q3 = {0,0,0,0};
            float4 h4;
            h4 = hC[0]; DOT4(q0,b00,h4) DOT4(q1,b10,h4) DOT4(q2,b20,h4) DOT4(q3,wl[0],h4)
            h4 = hC[1]; DOT4(q0,b01,h4) DOT4(q1,b11,h4) DOT4(q2,b21,h4) DOT4(q3,wl[1],h4)
            h4 = hC[2]; DOT4(q0,b02,h4) DOT4(q1,b12,h4) DOT4(q2,b22,h4) DOT4(q3,wl[2],h4)
            h4 = hC[3]; DOT4(q0,b03,h4) DOT4(q1,b13,h4) DOT4(q2,b23,h4) DOT4(q3,wl[3],h4)
            h4 = hC[4]; DOT4(q0,b04,h4) DOT4(q1,b14,h4) DOT4(q2,b24,h4) DOT4(q3,wl[4],h4)
            h4 = hC[5]; DOT4(q0,b05,h4) DOT4(q1,b15,h4) DOT4(q2,b25,h4) DOT4(q3,wl[5],h4)
            float s0 = (q0.x + q0.y) + (q0.z + q0.w);
            float s1 = (q1.x + q1.y) + (q1.z + q1.w);
            float s2 = (q2.x + q2.y) + (q2.z + q2.w);
            float s3 = (q3.x + q3.y) + (q3.z + q3.w);
            s0 = fmaf(mc0, biasC, s0); s1 = fmaf(mc1, biasC, s1);
            s2 = fmaf(mc2, biasC, s2); s3 = fmaf(mc3, biasC, s3);
            RED8(s0) RED8(s1) RED8(s2) RED8(s3)
            float po = 0.0f;
            if (kq == 0) {
                float gi = sigf(s0), gf = sigf(s1), gc = tanh_fast(s2), go = sigf(s3);
                c2 = gf * c2 + gi * gc;
                float h2v = go * tanh_fast(c2);
                h2b[wb * HID + u] = h2v;
                po = wl_u * h2v;
            }
            // wave-sum of the 8 unit-leaders, then one atomic per wave
            po = dpp_add<DPP_ROR8>(po);
            po += __shfl_xor(po, 16);
            po += __shfl_xor(po, 32);
            if ((tid & 63) == 0) atomicAdd(&out_s[t], po + ((tid == 0) ? bl0 : 0.0f));
        }
        // no trailing barrier needed: next step's L1 writes h1b[rd], which no
        // thread reads after this step's barrier (L2 reads h1b[wb]/h2b[rd]),
        // and all threads left L1(t) before the barrier released anyone.
    }
    __syncthreads();
    for (int i = tid; i < TLEN; i += NTHR) out[b * TLEN + i] = out_s[i];
}

extern "C" void kernel_launch(void* const* d_in, const int* in_sizes, int n_in,
                              void* d_out, int out_size, void* d_ws, size_t ws_size,
                              hipStream_t stream)
{
    (void)in_sizes; (void)n_in; (void)d_ws; (void)ws_size; (void)out_size;
    const float* x    = (const float*)d_in[0];
    const float* Wih0 = (const float*)d_in[1];
    const float* Whh0 = (const float*)d_in[2];
    const float* bih0 = (const float*)d_in[3];
    const float* bhh0 = (const float*)d_in[4];
    const float* Wih1 = (const float*)d_in[5];
    const float* Whh1 = (const float*)d_in[6];
    const float* bih1 = (const float*)d_in[7];
    const float* bhh1 = (const float*)d_in[8];
    const float* Wl   = (const float*)d_in[9];
    const float* bl   = (const float*)d_in[10];

    lstm2_fused<<<dim3(256), dim3(NTHR), 0, stream>>>(
        x, Wih0, Whh0, bih0, bhh0, Wih1, Whh1, bih1, bhh1, Wl, bl,
        (float*)d_out);
}